// Round 8
// baseline (86.145 us; speedup 1.0000x reference)
//
#include <hip/hip_runtime.h>
#include <hip/hip_fp16.h>

constexpr int ES = 7;
constexpr int CH = 256;
constexpr int FH = 200;
constexpr int FW = 304;
constexpr int HW = FH * FW;             // 60800
constexpr int CELLS = ES * ES;          // 49
constexpr int BOX_OUT = CH * CELLS;     // 12544 floats
constexpr int QCH = 64;                 // channels per gather quarter
constexpr int HW_TILES = HW / 64;       // 950
constexpr int CT_TILES = CH / 64;       // 4
constexpr int TILES_PER_BATCH = HW_TILES * CT_TILES;   // 3800

typedef float f32x4 __attribute__((ext_vector_type(4)));

struct TransSmem {
  float s_t[64][65];
};
struct GatherSmem {
  int   y0[ES]; int y1[ES]; int x0[ES];
  float fy[ES]; float fx[ES];
  alignas(16) float buf[QCH * CELLS];   // 12544 B
};
union ComboSmem {
  TransSmem t;
  GatherSmem g;
};

// ---------------------------------------------------------------------------
// Combo kernel. Blocks [0, g_blocks): gather box-QUARTERS of batch-pair
// `gather_pair` (wrong-pair boxes early-exit; no sync/spin anywhere, so
// dispatch order affects only performance). Blocks [g_blocks, ...):
// transpose the two batches of `trans_pair` (NCHW f32 -> NHWC f16), fm reads
// nontemporal so the streamed input doesn't evict fmt from L3.
// ---------------------------------------------------------------------------
__global__ __launch_bounds__(256)
void combo_kernel(const float* __restrict__ fm,
                  __half* __restrict__ fmt0,
                  __half* __restrict__ fmt1,
                  const float* __restrict__ boxes,
                  const int* __restrict__ assoc,
                  float* __restrict__ out,
                  int g_blocks, int gather_pair, int trans_pair) {
  __shared__ ComboSmem smem;
  const int t   = threadIdx.x;
  const int bid = blockIdx.x;

  if (bid < g_blocks) {
    // ---------------- gather (box-quarter) ----------------
    const int n = bid >> 2;
    const int q = bid & 3;
    const int a = assoc[n];
    if ((a >> 1) != gather_pair) return;

    GatherSmem& g = smem.g;
    if (t < 2 * ES) {
      const int axis = t / ES;   // 0 = y, 1 = x
      const int i = t % ES;
      const float start = boxes[n * 4 + axis];
      const float stop  = boxes[n * 4 + 2 + axis];
      const float step  = (stop - start) * (1.0f / (float)(ES - 1));
      const float cc = fminf((float)i * step + start, stop);
      const float fl = floorf(cc);
      if (axis == 0) {
        g.y0[i] = (int)fl;
        g.y1[i] = (int)ceilf(cc);
        g.fy[i] = cc - fl;
      } else {
        int x0 = (int)fl;
        float f = cc - fl;
        if (x0 >= FW - 1) { x0 = FW - 2; f = 1.0f; }
        g.x0[i] = x0;
        g.fx[i] = f;
      }
    }
    __syncthreads();

    const int cgi = t & 7;     // 8-channel group within the quarter
    const int sub = t >> 3;    // cell phase 0..31
    const __half* base = ((gather_pair == 0) ? fmt0 : fmt1)
                         + (size_t)(a & 1) * ((size_t)CH * HW)
                         + q * QCH + cgi * 8;

    #pragma unroll
    for (int rep = 0; rep < 2; ++rep) {
      const int cell = sub + rep * 32;
      if (cell < CELLS) {
        const int i = cell / ES;
        const int j = cell % ES;
        const int y0 = g.y0[i], y1 = g.y1[i], x0 = g.x0[j];
        const float fy = g.fy[i], fx = g.fx[j];
        const float w00 = (1.0f - fy) * (1.0f - fx);
        const float w01 = (1.0f - fy) * fx;
        const float w10 = fy * (1.0f - fx);
        const float w11 = fy * fx;

        const size_t o0 = (size_t)(y0 * FW + x0) * CH;
        const size_t o1 = (size_t)(y1 * FW + x0) * CH;
        const uint4 q00 = *(const uint4*)(base + o0);
        const uint4 q01 = *(const uint4*)(base + o0 + CH);
        const uint4 q10 = *(const uint4*)(base + o1);
        const uint4 q11 = *(const uint4*)(base + o1 + CH);

        const __half2* a00 = (const __half2*)&q00;
        const __half2* a01 = (const __half2*)&q01;
        const __half2* a10 = (const __half2*)&q10;
        const __half2* a11 = (const __half2*)&q11;

        const int lc = cgi * 8;
        #pragma unroll
        for (int p = 0; p < 4; ++p) {
          const float2 f00 = __half22float2(a00[p]);
          const float2 f01 = __half22float2(a01[p]);
          const float2 f10 = __half22float2(a10[p]);
          const float2 f11 = __half22float2(a11[p]);
          const float rx = w00 * f00.x + w01 * f01.x + w10 * f10.x + w11 * f11.x;
          const float ry = w00 * f00.y + w01 * f01.y + w10 * f10.y + w11 * f11.y;
          g.buf[(lc + 2 * p + 0) * CELLS + cell] = rx;
          g.buf[(lc + 2 * p + 1) * CELLS + cell] = ry;
        }
      }
    }
    __syncthreads();

    f32x4* __restrict__ outv =
        (f32x4*)(out + (size_t)n * BOX_OUT + (size_t)q * QCH * CELLS);
    const f32x4* bufv = (const f32x4*)g.buf;
    for (int k = t; k < QCH * CELLS / 4; k += 256) {
      __builtin_nontemporal_store(bufv[k], outv + k);
    }
    return;
  }

  // ---------------- transpose ----------------
  if (trans_pair < 0) return;
  const int tb  = bid - g_blocks;
  const int z   = tb / TILES_PER_BATCH;     // batch within pair (0/1)
  const int r   = tb % TILES_PER_BATCH;
  const int hwt = (r % HW_TILES) * 64;
  const int ct  = (r / HW_TILES) * 64;
  const int b   = trans_pair * 2 + z;
  __half* fmtw = ((trans_pair == 0) ? fmt0 : fmt1) + (size_t)z * CH * HW;

  TransSmem& ts = smem.t;
  {
    const int hw4  = t % 16;
    const int c_lo = t / 16;
    #pragma unroll
    for (int rr = 0; rr < 4; ++rr) {
      const int c = c_lo + rr * 16;
      const f32x4 v = __builtin_nontemporal_load(
          (const f32x4*)(fm + ((size_t)(b * CH + ct + c)) * HW + hwt + hw4 * 4));
      ts.s_t[c][hw4 * 4 + 0] = v.x;
      ts.s_t[c][hw4 * 4 + 1] = v.y;
      ts.s_t[c][hw4 * 4 + 2] = v.z;
      ts.s_t[c][hw4 * 4 + 3] = v.w;
    }
  }
  __syncthreads();
  {
    const int c8 = t % 8;
    const int hl = t / 8;
    #pragma unroll
    for (int rr = 0; rr < 2; ++rr) {
      const int h = hl + rr * 32;
      union { uint4 u; __half hh[8]; } o;
      #pragma unroll
      for (int e = 0; e < 8; ++e) {
        o.hh[e] = __float2half(ts.s_t[c8 * 8 + e][h]);
      }
      *(uint4*)(fmtw + ((size_t)(hwt + h)) * CH + ct + c8 * 8) = o.u;
    }
  }
}

// ---------------------------------------------------------------------------
// Fallback: direct NCHW gather (correct, slower) if ws too small / batch != 4.
// ---------------------------------------------------------------------------
__global__ __launch_bounds__(256)
void roi_align_fallback_kernel(const float* __restrict__ fm,
                               const float* __restrict__ boxes,
                               const int* __restrict__ assoc,
                               float* __restrict__ out) {
  __shared__ int   s_y0[ES];
  __shared__ int   s_y1[ES];
  __shared__ int   s_x0[ES];
  __shared__ float s_fy[ES];
  __shared__ float s_fx[ES];
  __shared__ __align__(16) float s_buf[BOX_OUT];

  const int n = blockIdx.x;
  const int t = threadIdx.x;

  if (t < 2 * ES) {
    const int axis = t / ES;
    const int i = t % ES;
    const float start = boxes[n * 4 + axis];
    const float stop  = boxes[n * 4 + 2 + axis];
    const float step  = (stop - start) * (1.0f / (float)(ES - 1));
    const float cc = fminf((float)i * step + start, stop);
    const float fl = floorf(cc);
    if (axis == 0) {
      s_y0[i] = (int)fl;
      s_y1[i] = (int)ceilf(cc);
      s_fy[i] = cc - fl;
    } else {
      int x0 = (int)fl;
      float f = cc - fl;
      if (x0 >= FW - 1) { x0 = FW - 2; f = 1.0f; }
      s_x0[i] = x0;
      s_fx[i] = f;
    }
  }
  __syncthreads();

  const int c = t;
  const int b = assoc[n];
  const float* plane = fm + ((size_t)b * CH + c) * (size_t)HW;

  #pragma unroll
  for (int i = 0; i < ES; ++i) {
    const float* r0 = plane + s_y0[i] * FW;
    const float* r1 = plane + s_y1[i] * FW;
    const float fy = s_fy[i];
    #pragma unroll
    for (int j = 0; j < ES; ++j) {
      const int   x0 = s_x0[j];
      const float fx = s_fx[j];
      const float v00 = r0[x0];
      const float v01 = r0[x0 + 1];
      const float v10 = r1[x0];
      const float v11 = r1[x0 + 1];
      const float top = v00 + fx * (v01 - v00);
      const float bot = v10 + fx * (v11 - v10);
      s_buf[c * CELLS + i * ES + j] = top + fy * (bot - top);
    }
  }
  __syncthreads();

  float4* __restrict__ outv = (float4*)(out + (size_t)n * BOX_OUT);
  const float4* bufv = (const float4*)s_buf;
  for (int k = t; k < BOX_OUT / 4; k += 256) {
    outv[k] = bufv[k];
  }
}

extern "C" void kernel_launch(void* const* d_in, const int* in_sizes, int n_in,
                              void* d_out, int out_size, void* d_ws, size_t ws_size,
                              hipStream_t stream) {
  const float* fm    = (const float*)d_in[0];
  const float* boxes = (const float*)d_in[1];
  const int*   assoc = (const int*)d_in[2];
  float* out = (float*)d_out;
  const int n_boxes = in_sizes[2];                 // 1024
  const int nbatch  = in_sizes[0] / (CH * HW);     // 4

  const size_t need = (size_t)4 * CH * HW * sizeof(__half);   // 124.5 MB
  if (nbatch == 4 && ws_size >= need) {
    __half* fmt0 = (__half*)d_ws;                           // batches 0,1
    __half* fmt1 = fmt0 + (size_t)2 * CH * HW;              // batches 2,3
    const int gB = n_boxes * 4;                             // 4096 quarters
    const int tB = 2 * TILES_PER_BATCH;                     // 7600
    // L1: transpose pair 0.
    combo_kernel<<<tB, 256, 0, stream>>>(fm, fmt0, fmt1, boxes, assoc, out,
                                         0, -1, 0);
    // L2: gather pair 0 (dispatched first, hides under transpose) + T pair 1.
    combo_kernel<<<gB + tB, 256, 0, stream>>>(fm, fmt0, fmt1, boxes, assoc, out,
                                              gB, 0, 1);
    // L3: gather pair 1.
    combo_kernel<<<gB, 256, 0, stream>>>(fm, fmt0, fmt1, boxes, assoc, out,
                                         gB, 1, -1);
  } else {
    roi_align_fallback_kernel<<<n_boxes, 256, 0, stream>>>(fm, boxes, assoc, out);
  }
}

// Round 9
// 83.683 us; speedup vs baseline: 1.0294x; 1.0294x over previous
//
#include <hip/hip_runtime.h>
#include <hip/hip_fp16.h>

constexpr int ES = 7;
constexpr int CH = 256;
constexpr int FH = 200;
constexpr int FW = 304;
constexpr int HW = FH * FW;             // 60800
constexpr int CELLS = ES * ES;          // 49
constexpr int BOX_OUT = CH * CELLS;     // 12544 floats
constexpr int QCH = 64;                 // channels per gather quarter

typedef float f32x4 __attribute__((ext_vector_type(4)));

// ---------------------------------------------------------------------------
// Kernel 1: NCHW f32 -> NHWC f16 transpose (all 4 batches).
// fm reads are NONTEMPORAL (streamed, no reuse) so they don't evict the
// freshly written fmt from L3. fmt writes allocate normally (gather reuses).
// 64(ch) x 64(hw) tiles, LDS padded [64][65] (2-way max = free on CDNA4).
// ---------------------------------------------------------------------------
__global__ __launch_bounds__(256)
void nchw_to_nhwc_f16_kernel(const float* __restrict__ fm,
                             __half* __restrict__ fmt) {
  __shared__ float s_t[64][65];
  const int t   = threadIdx.x;
  const int hwt = blockIdx.x * 64;
  const int ct  = blockIdx.y * 64;
  const int b   = blockIdx.z;

  // Phase 1: coalesced float4 nontemporal reads along hw.
  {
    const int hw4  = t % 16;
    const int c_lo = t / 16;
    #pragma unroll
    for (int r = 0; r < 4; ++r) {
      const int c = c_lo + r * 16;
      const f32x4 v = __builtin_nontemporal_load(
          (const f32x4*)(fm + ((size_t)(b * CH + ct + c)) * HW + hwt + hw4 * 4));
      s_t[c][hw4 * 4 + 0] = v.x;
      s_t[c][hw4 * 4 + 1] = v.y;
      s_t[c][hw4 * 4 + 2] = v.z;
      s_t[c][hw4 * 4 + 3] = v.w;
    }
  }
  __syncthreads();

  // Phase 2: gather 8 channels at fixed hw, convert to f16, 16B store.
  {
    const int c8 = t % 8;
    const int hl = t / 8;
    #pragma unroll
    for (int r = 0; r < 2; ++r) {
      const int h = hl + r * 32;
      union { uint4 u; __half hh[8]; } o;
      #pragma unroll
      for (int e = 0; e < 8; ++e) {
        o.hh[e] = __float2half(s_t[c8 * 8 + e][h]);
      }
      *(uint4*)(fmt + ((size_t)b * HW + hwt + h) * CH + ct + c8 * 8) = o.u;
    }
  }
}

// ---------------------------------------------------------------------------
// Kernel 2: RoI-align gather on NHWC f16, box-QUARTER granularity.
// Block = (box, 64-channel quarter): 4096 blocks x 12.5 KB LDS -> ~6-8
// blocks/CU of memory-level parallelism. Tap reads hit L3 (fmt resident);
// output stores are nontemporal (never re-read, keep L3 for fmt).
// ---------------------------------------------------------------------------
__global__ __launch_bounds__(256)
void roi_gather_q_kernel(const __half* __restrict__ fmt,
                         const float* __restrict__ boxes,
                         const int* __restrict__ assoc,
                         float* __restrict__ out) {
  __shared__ int   s_y0[ES];
  __shared__ int   s_y1[ES];
  __shared__ int   s_x0[ES];
  __shared__ float s_fy[ES];
  __shared__ float s_fx[ES];
  __shared__ __align__(16) float s_buf[QCH * CELLS];

  const int n = blockIdx.x;
  const int q = blockIdx.y;
  const int t = threadIdx.x;

  if (t < 2 * ES) {
    const int axis = t / ES;   // 0 = y, 1 = x
    const int i = t % ES;
    const float start = boxes[n * 4 + axis];
    const float stop  = boxes[n * 4 + 2 + axis];
    const float step  = (stop - start) * (1.0f / (float)(ES - 1));
    const float cc = fminf((float)i * step + start, stop);
    const float fl = floorf(cc);
    if (axis == 0) {
      s_y0[i] = (int)fl;
      s_y1[i] = (int)ceilf(cc);
      s_fy[i] = cc - fl;
    } else {
      int x0 = (int)fl;
      float f = cc - fl;
      if (x0 >= FW - 1) { x0 = FW - 2; f = 1.0f; }
      s_x0[i] = x0;
      s_fx[i] = f;
    }
  }
  __syncthreads();

  const int cgi = t & 7;     // 8-channel group within the quarter
  const int sub = t >> 3;    // cell phase 0..31
  const __half* base = fmt + (size_t)assoc[n] * HW * CH + q * QCH + cgi * 8;

  for (int cell = sub; cell < CELLS; cell += 32) {
    const int i = cell / ES;
    const int j = cell % ES;
    const int y0 = s_y0[i], y1 = s_y1[i], x0 = s_x0[j];
    const float fy = s_fy[i], fx = s_fx[j];
    const float w00 = (1.0f - fy) * (1.0f - fx);
    const float w01 = (1.0f - fy) * fx;
    const float w10 = fy * (1.0f - fx);
    const float w11 = fy * fx;

    const size_t o0 = (size_t)(y0 * FW + x0) * CH;
    const size_t o1 = (size_t)(y1 * FW + x0) * CH;
    const uint4 q00 = *(const uint4*)(base + o0);
    const uint4 q01 = *(const uint4*)(base + o0 + CH);
    const uint4 q10 = *(const uint4*)(base + o1);
    const uint4 q11 = *(const uint4*)(base + o1 + CH);

    const __half2* a00 = (const __half2*)&q00;
    const __half2* a01 = (const __half2*)&q01;
    const __half2* a10 = (const __half2*)&q10;
    const __half2* a11 = (const __half2*)&q11;

    const int lc = cgi * 8;
    #pragma unroll
    for (int p = 0; p < 4; ++p) {
      const float2 f00 = __half22float2(a00[p]);
      const float2 f01 = __half22float2(a01[p]);
      const float2 f10 = __half22float2(a10[p]);
      const float2 f11 = __half22float2(a11[p]);
      const float rx = w00 * f00.x + w01 * f01.x + w10 * f10.x + w11 * f11.x;
      const float ry = w00 * f00.y + w01 * f01.y + w10 * f10.y + w11 * f11.y;
      s_buf[(lc + 2 * p + 0) * CELLS + cell] = rx;
      s_buf[(lc + 2 * p + 1) * CELLS + cell] = ry;
    }
  }
  __syncthreads();

  // Coalesced nontemporal float4 stores of this quarter's (64,7,7) block.
  f32x4* __restrict__ outv =
      (f32x4*)(out + (size_t)n * BOX_OUT + (size_t)q * QCH * CELLS);
  const f32x4* bufv = (const f32x4*)s_buf;
  for (int k = t; k < QCH * CELLS / 4; k += 256) {
    __builtin_nontemporal_store(bufv[k], outv + k);
  }
}

// ---------------------------------------------------------------------------
// Fallback: direct NCHW gather (correct, slower) if ws too small.
// ---------------------------------------------------------------------------
__global__ __launch_bounds__(256)
void roi_align_fallback_kernel(const float* __restrict__ fm,
                               const float* __restrict__ boxes,
                               const int* __restrict__ assoc,
                               float* __restrict__ out) {
  __shared__ int   s_y0[ES];
  __shared__ int   s_y1[ES];
  __shared__ int   s_x0[ES];
  __shared__ float s_fy[ES];
  __shared__ float s_fx[ES];
  __shared__ __align__(16) float s_buf[BOX_OUT];

  const int n = blockIdx.x;
  const int t = threadIdx.x;

  if (t < 2 * ES) {
    const int axis = t / ES;
    const int i = t % ES;
    const float start = boxes[n * 4 + axis];
    const float stop  = boxes[n * 4 + 2 + axis];
    const float step  = (stop - start) * (1.0f / (float)(ES - 1));
    const float cc = fminf((float)i * step + start, stop);
    const float fl = floorf(cc);
    if (axis == 0) {
      s_y0[i] = (int)fl;
      s_y1[i] = (int)ceilf(cc);
      s_fy[i] = cc - fl;
    } else {
      int x0 = (int)fl;
      float f = cc - fl;
      if (x0 >= FW - 1) { x0 = FW - 2; f = 1.0f; }
      s_x0[i] = x0;
      s_fx[i] = f;
    }
  }
  __syncthreads();

  const int c = t;
  const int b = assoc[n];
  const float* plane = fm + ((size_t)b * CH + c) * (size_t)HW;

  #pragma unroll
  for (int i = 0; i < ES; ++i) {
    const float* r0 = plane + s_y0[i] * FW;
    const float* r1 = plane + s_y1[i] * FW;
    const float fy = s_fy[i];
    #pragma unroll
    for (int j = 0; j < ES; ++j) {
      const int   x0 = s_x0[j];
      const float fx = s_fx[j];
      const float v00 = r0[x0];
      const float v01 = r0[x0 + 1];
      const float v10 = r1[x0];
      const float v11 = r1[x0 + 1];
      const float top = v00 + fx * (v01 - v00);
      const float bot = v10 + fx * (v11 - v10);
      s_buf[c * CELLS + i * ES + j] = top + fy * (bot - top);
    }
  }
  __syncthreads();

  float4* __restrict__ outv = (float4*)(out + (size_t)n * BOX_OUT);
  const float4* bufv = (const float4*)s_buf;
  for (int k = t; k < BOX_OUT / 4; k += 256) {
    outv[k] = bufv[k];
  }
}

extern "C" void kernel_launch(void* const* d_in, const int* in_sizes, int n_in,
                              void* d_out, int out_size, void* d_ws, size_t ws_size,
                              hipStream_t stream) {
  const float* fm    = (const float*)d_in[0];
  const float* boxes = (const float*)d_in[1];
  const int*   assoc = (const int*)d_in[2];
  float* out = (float*)d_out;
  const int n_boxes = in_sizes[2];                 // 1024
  const int nbatch  = in_sizes[0] / (CH * HW);     // 4

  const size_t need = (size_t)nbatch * CH * HW * sizeof(__half);   // 124.5 MB
  if (ws_size >= need) {
    __half* fmt = (__half*)d_ws;
    dim3 tgrid(HW / 64, CH / 64, nbatch);
    nchw_to_nhwc_f16_kernel<<<tgrid, 256, 0, stream>>>(fm, fmt);
    dim3 ggrid(n_boxes, CH / QCH);
    roi_gather_q_kernel<<<ggrid, 256, 0, stream>>>(fmt, boxes, assoc, out);
  } else {
    roi_align_fallback_kernel<<<n_boxes, 256, 0, stream>>>(fm, boxes, assoc, out);
  }
}